// Round 18
// baseline (58.234 us; speedup 1.0000x reference)
//
#include <hip/hip_runtime.h>
#include <math.h>
#include <stdint.h>

#define D_MODEL 512
#define D_STATE 16
#define NSEQ    2048
#define NBATCH  4
#define EPSF    1e-8f
#define LN_EPSF 1e-5f
#define DT      (1.0f / 2048.0f)

typedef __attribute__((ext_vector_type(8))) short short8;
typedef __attribute__((ext_vector_type(4))) float floatx4;

__device__ __forceinline__ ushort f2bf(float f) {
    uint32_t u = __float_as_uint(f);
    return (ushort)((u + 0x7fffu + ((u >> 16) & 1u)) >> 16);
}

// ---------------------------------------------------------------------------
// kP (512 blocks x 256): byte-identical to the validated R7/R12/R14 version.
// ---------------------------------------------------------------------------
__global__ __launch_bounds__(256) void kP(const float* __restrict__ x,
                                          const float* __restrict__ A_log,
                                          const float* __restrict__ W_B,
                                          const float* __restrict__ Wg,
                                          ushort* __restrict__ wgb,
                                          float* __restrict__ hL,
                                          float* __restrict__ states) {
    __shared__ float wb[D_STATE][D_MODEL + 4];
    __shared__ float bbars[16], abars[16];
    __shared__ float w4[4][16];
    const int tid = threadIdx.x, lane = tid & 63, wave = tid >> 6;

    if (tid < 64) {                       // W_gate cvt slice
        int i = blockIdx.x * 64 + tid;
        const float4* sp = (const float4*)Wg + (size_t)i * 2;
        float4 a = sp[0], b = sp[1];
        float v[8] = {a.x, a.y, a.z, a.w, b.x, b.y, b.z, b.w};
        short8 o;
        #pragma unroll
        for (int j = 0; j < 8; ++j) o[j] = (short)f2bf(v[j]);
        *(short8*)(wgb + (size_t)i * 8) = o;
    }
    if (tid < 16) {
        float A    = -fminf(fmaxf(expf(A_log[tid]), EPSF), 10.0f);
        float Abar = expf(A * DT);
        abars[tid] = Abar;
        bbars[tid] = (fabsf(A) > EPSF) ? (Abar - 1.0f) / (A + EPSF) : DT;
    }
    __syncthreads();
    for (int i = tid; i < D_STATE * D_MODEL; i += 256) {
        int s = i >> 9, m = i & 511;
        wb[s][m] = W_B[i] * bbars[s];
    }
    __syncthreads();

    const int s    = lane & 15;
    const int q    = lane >> 4;
    const int rloc = q + (wave << 2);
    const int row  = blockIdx.x * 16 + rloc;
    const float* xr = x + (size_t)row * D_MODEL;

    float acc = 0.f;
    #pragma unroll 4
    for (int m = 0; m < D_MODEL; m += 4) {
        float4 xv = *(const float4*)(xr + m);
        float4 wv = *(const float4*)(&wb[s][m]);
        acc += xv.x * wv.x + xv.y * wv.y + xv.z * wv.z + xv.w * wv.w;
    }

    float abar = abars[s];
    float a = abar, b = acc;
    {
        float ap = __shfl_up(a, 16), bp = __shfl_up(b, 16);
        if (lane >= 16) { b = a * bp + b; a = a * ap; }
    }
    {
        float ap = __shfl_up(a, 32), bp = __shfl_up(b, 32);
        if (lane >= 32) { b = a * bp + b; a = a * ap; }
    }
    if (q == 3) w4[wave][s] = b;
    __syncthreads();
    float a4 = abar * abar; a4 = a4 * a4;
    float pb = 0.f;
    for (int w = 0; w < wave; ++w) pb = a4 * pb + w4[w][s];
    float hloc = a * pb + b;

    hL[(size_t)row * D_STATE + s] = hloc;
    if (rloc == 15) states[(size_t)blockIdx.x * D_STATE + s] = hloc;
}

// ---------------------------------------------------------------------------
// kG (256 blocks x 512 thr, 1 block/CU): M-tile 128 x N-quarter 128.
// Wg-quarter (128KB) staged in LDS ONCE (single drain), then 8 barrier-free
// K-steps. A preloaded in regs. Writes pre-LN v to out + per-row (sum,sumsq)
// partials. bid: rt = bid>>2 (row tile), cq = bid&3 (col quarter).
// ---------------------------------------------------------------------------
__global__ __launch_bounds__(512) void kG(
    const float*  __restrict__ x,      // (8192,512)
    const ushort* __restrict__ Wg,     // bf16 (512,512)
    const float*  __restrict__ hL,     // (8192,16)
    const float*  __restrict__ states, // (512,16)
    const float*  __restrict__ A_log,
    const float*  __restrict__ W_C,    // (512,16)
    const float*  __restrict__ Dvec,
    const float*  __restrict__ bg,
    float* __restrict__ partials,      // (4,8192,2)
    float* __restrict__ out) {
    __shared__ ushort Wgs[128 * D_MODEL];   // 128 KB (stg aliases this in prologue)
    __shared__ float  hsf[128][D_STATE];    // 8 KB

    const int tid  = threadIdx.x;             // 0..511
    const int lane = tid & 63, wave = tid >> 6;
    const int rt   = blockIdx.x >> 2;         // 0..63
    const int cq   = blockIdx.x & 3;          // 0..3
    const int r0   = rt * 128;
    const int fr   = lane & 15, kg = lane >> 4;
    const int rbase = r0 + wave * 16;         // wave's 16-row slab

    // ---- A preload: wave's 16x512 A-slab as bf16 in regs (64 VGPR) ----
    short8 afp[8][2];
    #pragma unroll
    for (int t = 0; t < 8; ++t) {
        const float* ap = x + (size_t)(rbase + fr) * D_MODEL + t * 64 + kg * 8;
        float4 u0 = *(const float4*)ap;
        float4 u1 = *(const float4*)(ap + 4);
        float4 v0 = *(const float4*)(ap + 32);
        float4 v1 = *(const float4*)(ap + 36);
        float uu[8] = {u0.x,u0.y,u0.z,u0.w,u1.x,u1.y,u1.z,u1.w};
        float vv[8] = {v0.x,v0.y,v0.z,v0.w,v1.x,v1.y,v1.z,v1.w};
        #pragma unroll
        for (int e = 0; e < 8; ++e) {
            afp[t][0][e] = (short)f2bf(uu[e]);
            afp[t][1][e] = (short)f2bf(vv[e]);
        }
    }

    // ---- chunk-prefix combine -> hsf (block = chunks rt*8 .. rt*8+7) ----
    float* stg = (float*)Wgs;
    const int c0    = (rt & 15) * 8;          // chunks before, within batch
    const int cbase = (rt >> 4) * 128;        // batch's first chunk
    for (int i = tid; i < (c0 + 8) * 16; i += 512)
        stg[i] = states[(size_t)cbase * 16 + i];
    __syncthreads();
    {
        int s = tid & 15;
        float A   = -fminf(fmaxf(expf(A_log[s]), EPSF), 10.0f);
        float a16 = expf(A * DT * 16.0f);
        #pragma unroll
        for (int it = 0; it < 4; ++it) {
            int nloc = (tid >> 4) + it * 32;        // 0..127
            int nch  = c0 + (nloc >> 4);
            float p = 0.f;
            for (int cc = 0; cc < nch; ++cc) p = a16 * p + stg[cc * 16 + s];
            float hv = expf(A * DT * (float)((nloc & 15) + 1)) * p
                     + hL[(size_t)(r0 + nloc) * D_STATE + s];
            hsf[nloc][s] = fminf(fmaxf(hv, -10.f), 10.f);
        }
    }
    __syncthreads();          // stg reads done before Wgs staged

    // ---- stage Wg-quarter ONCE: 128 rows x 512 k, pre-swizzled source ----
    // dest linear: issue i, addr = i*8192 + tid*16 -> row = i*8+(tid>>6),
    // slot si = tid&63; t = si>>3, sg = si&7, logical g = sg ^ (row&7).
    {
        const int rloc = tid >> 6;            // 0..7 within issue
        const int si   = tid & 63;
        const int t_   = si >> 3, sg = si & 7;
        #pragma unroll
        for (int is = 0; is < 16; ++is) {
            int r  = is * 8 + rloc;
            int g  = sg ^ (r & 7);
            const ushort* gsrc = Wg + (size_t)(cq * 128 + r) * D_MODEL + t_ * 64 + g * 8;
            __builtin_amdgcn_global_load_lds(
                (const __attribute__((address_space(1))) void*)gsrc,
                (__attribute__((address_space(3))) void*)((char*)Wgs + is * 8192 + tid * 16),
                16, 0, 0);
        }
    }
    __syncthreads();          // SINGLE drain: whole quarter resident

    // ---- 8 barrier-free K-steps ----
    floatx4 acc[8] = {};
    #pragma unroll
    for (int t = 0; t < 8; ++t) {
        #pragma unroll
        for (int j = 0; j < 8; ++j) {
            int rb = j * 16 + fr;             // block-local col 0..127
            const ushort* base = Wgs + (size_t)rb * D_MODEL;
            short8 b0 = *(const short8*)(base + (t * 8 + ((kg    ) ^ (rb & 7))) * 8);
            short8 b1 = *(const short8*)(base + (t * 8 + ((kg + 4) ^ (rb & 7))) * 8);
            acc[j] = __builtin_amdgcn_mfma_f32_16x16x32_bf16(afp[t][0], b0, acc[j], 0, 0, 0);
            acc[j] = __builtin_amdgcn_mfma_f32_16x16x32_bf16(afp[t][1], b1, acc[j], 0, 0, 0);
        }
    }

    // ---- epilogue: y = h@W_C^T (f32) + D*x, blend; 128-col partial sums ----
    float vsum[4] = {}, vsq[4] = {};
    #pragma unroll
    for (int j = 0; j < 8; ++j) {
        int col = cq * 128 + j * 16 + fr;
        float dv = Dvec[col], bgv = bg[col];
        const float4* wcp = (const float4*)(W_C + (size_t)col * D_STATE);
        float4 w0 = wcp[0], w1 = wcp[1], w2 = wcp[2], w3 = wcp[3];
        #pragma unroll
        for (int q = 0; q < 4; ++q) {
            int rloc = wave * 16 + kg * 4 + q;         // block-local row
            float xv = x[(size_t)(r0 + rloc) * D_MODEL + col];
            const float* hp = hsf[rloc];
            float yv = dv * xv
                + hp[0]*w0.x + hp[1]*w0.y + hp[2]*w0.z + hp[3]*w0.w
                + hp[4]*w1.x + hp[5]*w1.y + hp[6]*w1.z + hp[7]*w1.w
                + hp[8]*w2.x + hp[9]*w2.y + hp[10]*w2.z + hp[11]*w2.w
                + hp[12]*w3.x + hp[13]*w3.y + hp[14]*w3.z + hp[15]*w3.w;
            float lg = acc[j][q] + bgv;
            float gt = 1.f / (1.f + expf(-lg));
            float v  = gt * yv + (1.f - gt) * xv;
            acc[j][q] = v;
            vsum[q] += v;
            vsq[q]  += v * v;
        }
    }
    #pragma unroll
    for (int j = 0; j < 8; ++j) {              // store pre-LN v
        int col = cq * 128 + j * 16 + fr;
        #pragma unroll
        for (int q = 0; q < 4; ++q)
            out[(size_t)(r0 + wave * 16 + kg * 4 + q) * D_MODEL + col] = acc[j][q];
    }
    #pragma unroll
    for (int off = 1; off < 16; off <<= 1) {   // reduce over fr
        #pragma unroll
        for (int q = 0; q < 4; ++q) {
            vsum[q] += __shfl_xor(vsum[q], off);
            vsq[q]  += __shfl_xor(vsq[q], off);
        }
    }
    if (fr == 0) {
        #pragma unroll
        for (int q = 0; q < 4; ++q) {
            size_t row = (size_t)(r0 + wave * 16 + kg * 4 + q);
            partials[((size_t)cq * 8192 + row) * 2 + 0] = vsum[q];
            partials[((size_t)cq * 8192 + row) * 2 + 1] = vsq[q];
        }
    }
}

// ---------------------------------------------------------------------------
// kLN (2048 blocks x 256): wave per row; combine 4 quarter-partials,
// normalize out in place.
// ---------------------------------------------------------------------------
__global__ __launch_bounds__(256) void kLN(const float* __restrict__ partials,
                                           const float* __restrict__ gamma,
                                           const float* __restrict__ beta,
                                           float* __restrict__ out) {
    const int tid  = threadIdx.x;
    const int lane = tid & 63, wave = tid >> 6;
    const size_t row = (size_t)blockIdx.x * 4 + wave;

    float s = 0.f, ss = 0.f;
    #pragma unroll
    for (int cqq = 0; cqq < 4; ++cqq) {
        s  += partials[((size_t)cqq * 8192 + row) * 2 + 0];
        ss += partials[((size_t)cqq * 8192 + row) * 2 + 1];
    }
    const float mu = s * (1.f / (float)D_MODEL);
    const float var = ss * (1.f / (float)D_MODEL) - mu * mu;
    const float rs = rsqrtf(var + LN_EPSF);

    const int col0 = lane * 8;
    float* op = out + row * D_MODEL + col0;
    float4 v0 = *(float4*)op;
    float4 v1 = *(float4*)(op + 4);
    float4 g0 = *(const float4*)(gamma + col0);
    float4 g1 = *(const float4*)(gamma + col0 + 4);
    float4 b0 = *(const float4*)(beta + col0);
    float4 b1 = *(const float4*)(beta + col0 + 4);
    v0.x = (v0.x - mu) * rs * g0.x + b0.x;
    v0.y = (v0.y - mu) * rs * g0.y + b0.y;
    v0.z = (v0.z - mu) * rs * g0.z + b0.z;
    v0.w = (v0.w - mu) * rs * g0.w + b0.w;
    v1.x = (v1.x - mu) * rs * g1.x + b1.x;
    v1.y = (v1.y - mu) * rs * g1.y + b1.y;
    v1.z = (v1.z - mu) * rs * g1.z + b1.z;
    v1.w = (v1.w - mu) * rs * g1.w + b1.w;
    *(float4*)op = v0;
    *(float4*)(op + 4) = v1;
}

// ---------------------------------------------------------------------------
extern "C" void kernel_launch(void* const* d_in, const int* in_sizes, int n_in,
                              void* d_out, int out_size, void* d_ws, size_t ws_size,
                              hipStream_t stream) {
    const float* x     = (const float*)d_in[0];
    const float* A_log = (const float*)d_in[1];
    const float* W_B   = (const float*)d_in[2];
    const float* W_C   = (const float*)d_in[3];
    const float* Dv    = (const float*)d_in[4];
    const float* Wg    = (const float*)d_in[5];
    const float* bg    = (const float*)d_in[6];
    const float* gamma = (const float*)d_in[7];
    const float* beta  = (const float*)d_in[8];
    float* out = (float*)d_out;

    const int rows = NBATCH * NSEQ;                            // 8192

    ushort* wgb      = (ushort*)d_ws;                          // 512 KB
    float*  hL       = (float*)(wgb + (size_t)D_MODEL * D_MODEL);
    float*  states   = hL + (size_t)rows * D_STATE;            // 32 KB
    float*  partials = states + (size_t)512 * D_STATE;         // 256 KB

    hipLaunchKernelGGL(kP, dim3(rows / 16), dim3(256), 0, stream,
                       x, A_log, W_B, Wg, wgb, hL, states);
    hipLaunchKernelGGL(kG, dim3(256), dim3(512), 0, stream,
                       x, wgb, hL, states, A_log, W_C, Dv, bg, partials, out);
    hipLaunchKernelGGL(kLN, dim3(rows / 4), dim3(256), 0, stream,
                       partials, gamma, beta, out);
}

// Round 19
// 47.097 us; speedup vs baseline: 1.2365x; 1.2365x over previous
//
#include <hip/hip_runtime.h>
#include <math.h>
#include <stdint.h>

#define D_MODEL 512
#define D_STATE 16
#define NSEQ    2048
#define NBATCH  4
#define EPSF    1e-8f
#define LN_EPSF 1e-5f
#define DT      (1.0f / 2048.0f)

typedef __attribute__((ext_vector_type(8))) short short8;
typedef __attribute__((ext_vector_type(4))) float floatx4;

__device__ __forceinline__ ushort f2bf(float f) {
    uint32_t u = __float_as_uint(f);
    return (ushort)((u + 0x7fffu + ((u >> 16) & 1u)) >> 16);
}

// ---------------------------------------------------------------------------
// kP (512 blocks x 256): per block = 16 rows (= one scan chunk).
//  - W_gate f32->bf16 slice (64 thr)
//  - Bu dot: thread (s=lane&15, rloc=(lane>>4)+wave*4) over LDS-staged W_B*B_bar
//  - 16-row LOCAL scan (shfl offsets 16/32 + cross-wave LDS)
//  - writes hL[row][s] (unclipped local) + states[chunk][s] (chunk end)
// ---------------------------------------------------------------------------
__global__ __launch_bounds__(256) void kP(const float* __restrict__ x,
                                          const float* __restrict__ A_log,
                                          const float* __restrict__ W_B,
                                          const float* __restrict__ Wg,
                                          ushort* __restrict__ wgb,
                                          float* __restrict__ hL,
                                          float* __restrict__ states) {
    __shared__ float wb[D_STATE][D_MODEL + 4];
    __shared__ float bbars[16], abars[16];
    __shared__ float w4[4][16];
    const int tid = threadIdx.x, lane = tid & 63, wave = tid >> 6;

    if (tid < 64) {                       // W_gate cvt slice
        int i = blockIdx.x * 64 + tid;
        const float4* sp = (const float4*)Wg + (size_t)i * 2;
        float4 a = sp[0], b = sp[1];
        float v[8] = {a.x, a.y, a.z, a.w, b.x, b.y, b.z, b.w};
        short8 o;
        #pragma unroll
        for (int j = 0; j < 8; ++j) o[j] = (short)f2bf(v[j]);
        *(short8*)(wgb + (size_t)i * 8) = o;
    }
    if (tid < 16) {
        float A    = -fminf(fmaxf(expf(A_log[tid]), EPSF), 10.0f);
        float Abar = expf(A * DT);
        abars[tid] = Abar;
        bbars[tid] = (fabsf(A) > EPSF) ? (Abar - 1.0f) / (A + EPSF) : DT;
    }
    __syncthreads();
    for (int i = tid; i < D_STATE * D_MODEL; i += 256) {
        int s = i >> 9, m = i & 511;
        wb[s][m] = W_B[i] * bbars[s];
    }
    __syncthreads();

    const int s    = lane & 15;
    const int q    = lane >> 4;
    const int rloc = q + (wave << 2);
    const int row  = blockIdx.x * 16 + rloc;
    const float* xr = x + (size_t)row * D_MODEL;

    float acc = 0.f;
    #pragma unroll 4
    for (int m = 0; m < D_MODEL; m += 4) {
        float4 xv = *(const float4*)(xr + m);
        float4 wv = *(const float4*)(&wb[s][m]);
        acc += xv.x * wv.x + xv.y * wv.y + xv.z * wv.z + xv.w * wv.w;
    }

    float abar = abars[s];
    float a = abar, b = acc;
    {
        float ap = __shfl_up(a, 16), bp = __shfl_up(b, 16);
        if (lane >= 16) { b = a * bp + b; a = a * ap; }
    }
    {
        float ap = __shfl_up(a, 32), bp = __shfl_up(b, 32);
        if (lane >= 32) { b = a * bp + b; a = a * ap; }
    }
    if (q == 3) w4[wave][s] = b;
    __syncthreads();
    float a4 = abar * abar; a4 = a4 * a4;       // abar^4
    float pb = 0.f;
    for (int w = 0; w < wave; ++w) pb = a4 * pb + w4[w][s];
    float hloc = a * pb + b;

    hL[(size_t)row * D_STATE + s] = hloc;
    if (rloc == 15) states[(size_t)blockIdx.x * D_STATE + s] = hloc;
}

// ---------------------------------------------------------------------------
// kc (512 blocks x 256): chunk-prefix combine + h finalize + gate GEMM
// (bf16 MFMA, BK=32, 2 blocks/CU) + h@W_C^T + blend + LayerNorm.
// Exact R7-measured structure (46.9 us total).
// ---------------------------------------------------------------------------
#define CBM 16
#define BKC 32
__global__ __launch_bounds__(256) void kc_fused(
    const float*  __restrict__ x,      // (8192,512)
    const ushort* __restrict__ Wg,     // bf16 (512,512)
    const float*  __restrict__ hL,     // (8192,16) local-scan values
    const float*  __restrict__ states, // (512,16) chunk end states
    const float*  __restrict__ A_log,
    const float*  __restrict__ W_C,    // (512,16)
    const float*  __restrict__ Dvec,
    const float*  __restrict__ bg,
    const float*  __restrict__ gamma,
    const float*  __restrict__ beta,
    float* __restrict__ out) {
    __shared__ ushort Bsub[512 * BKC];     // 32 KB  (aliased as f32 stg in prologue)
    __shared__ ushort wcs[512 * 16];       // 16 KB
    __shared__ ushort Asub[CBM * BKC];     // 1 KB
    __shared__ ushort hs[CBM * 16];        // 512 B
    __shared__ float  red[4][CBM][2];      // 512 B

    const int tid  = threadIdx.x;
    const int lane = tid & 63, wave = tid >> 6;
    const int r0   = blockIdx.x * CBM;
    const int fr   = lane & 15, kg = lane >> 4;
    const int colw = wave * 128;

    // ---- prologue: stage chunk states (alias Bsub), W_C ----
    float* stg = (float*)Bsub;
    const int c0 = blockIdx.x & 127;               // chunks before ours (this b)
    for (int i = tid; i < c0 * 16; i += 256)
        stg[i] = states[(size_t)(blockIdx.x - c0) * 16 + i];

    #pragma unroll
    for (int it = 0; it < 4; ++it) {
        int idx = it * 256 + tid;                  // row*2 + g
        int row = idx >> 1, g = idx & 1;
        const float4* src = (const float4*)(W_C + (size_t)row * D_STATE + g * 8);
        float4 v0 = src[0], v1 = src[1];
        float v[8] = {v0.x,v0.y,v0.z,v0.w,v1.x,v1.y,v1.z,v1.w};
        short8 o;
        #pragma unroll
        for (int e = 0; e < 8; ++e) o[e] = (short)f2bf(v[e]);
        *(short8*)(wcs + row * 16 + (g ^ (row & 1)) * 8) = o;
    }
    __syncthreads();                               // stg ready

    {   // h finalize: thread (s=tid&15, nloc=tid>>4)
        int s = tid & 15, nloc = tid >> 4;
        float A   = -fminf(fmaxf(expf(A_log[s]), EPSF), 10.0f);
        float a16 = expf(A * DT * 16.0f);
        float p = 0.f;
        for (int cc = 0; cc < c0; ++cc) p = a16 * p + stg[cc * 16 + s];
        float hv = expf(A * DT * (float)(nloc + 1)) * p
                 + hL[(size_t)(r0 + nloc) * D_STATE + s];
        hv = fminf(fmaxf(hv, -10.f), 10.f);
        hs[nloc * 16 + (((s >> 3) ^ (nloc & 1)) * 8) + (s & 7)] = f2bf(hv);
    }

    // ---- gate GEMM: 16 K-steps of BK=32 ----
    floatx4 acc[8] = {};
    const int arow = tid >> 4;
    const int akp  = (tid & 15) * 2;

    for (int kc = 0; kc < D_MODEL; kc += BKC) {
        const float* axp = x + (size_t)(r0 + arow) * D_MODEL + kc + akp;
        float2 av = *(const float2*)axp;

        __syncthreads();               // prior frag-reads / prologue stg-reads done

        {
            int g = akp >> 3;
            int addr = arow * BKC + ((g ^ (arow & 3)) * 8) + (akp & 7);
            ushort2 o; o.x = f2bf(av.x); o.y = f2bf(av.y);
            *(ushort2*)(Asub + addr) = o;
        }
        #pragma unroll
        for (int is = 0; is < 8; ++is) {
            int row = is * 64 + (tid >> 2);
            int g   = (tid & 3) ^ (row & 3);
            const ushort* gsrc = Wg + (size_t)row * D_MODEL + kc + g * 8;
            __builtin_amdgcn_global_load_lds(
                (const __attribute__((address_space(1))) void*)gsrc,
                (__attribute__((address_space(3))) void*)((char*)Bsub + is * 4096 + tid * 16),
                16, 0, 0);
        }
        __syncthreads();               // tile ready

        short8 af = *(const short8*)(Asub + fr * BKC + ((kg ^ (fr & 3)) * 8));
        #pragma unroll
        for (int j = 0; j < 8; ++j) {
            int rb = colw + j * 16 + fr;
            short8 bv = *(const short8*)(Bsub + (size_t)rb * BKC + ((kg ^ (rb & 3)) * 8));
            acc[j] = __builtin_amdgcn_mfma_f32_16x16x32_bf16(af, bv, acc[j], 0, 0, 0);
        }
    }

    // ---- y_ssm = h @ W_C^T (K=32, upper half zero) ----
    const short8 z8 = short8{0,0,0,0,0,0,0,0};
    short8 ah = (kg < 2) ? *(const short8*)(hs + fr * 16 + ((kg ^ (fr & 1)) * 8)) : z8;
    floatx4 yc[8] = {};
    #pragma unroll
    for (int j = 0; j < 8; ++j) {
        int rb = colw + j * 16 + fr;
        short8 bw = (kg < 2) ? *(const short8*)(wcs + rb * 16 + ((kg ^ (rb & 1)) * 8)) : z8;
        yc[j] = __builtin_amdgcn_mfma_f32_16x16x32_bf16(ah, bw, yc[j], 0, 0, 0);
    }

    // ---- epilogue: blend + LN ----
    float vsum[4] = {}, vsq[4] = {};
    #pragma unroll
    for (int j = 0; j < 8; ++j) {
        int col = colw + j * 16 + fr;
        float dv = Dvec[col], bgv = bg[col];
        #pragma unroll
        for (int q = 0; q < 4; ++q) {
            int rl = kg * 4 + q;
            float xv = x[(size_t)(r0 + rl) * D_MODEL + col];
            float lg = acc[j][q] + bgv;
            float gt = 1.f / (1.f + expf(-lg));
            float yv = yc[j][q] + dv * xv;
            float v  = gt * yv + (1.f - gt) * xv;
            acc[j][q] = v;
            vsum[q] += v;
            vsq[q]  += v * v;
        }
    }
    #pragma unroll
    for (int off = 1; off < 16; off <<= 1) {
        #pragma unroll
        for (int q = 0; q < 4; ++q) {
            vsum[q] += __shfl_xor(vsum[q], off);
            vsq[q]  += __shfl_xor(vsq[q], off);
        }
    }
    if (fr == 0) {
        #pragma unroll
        for (int q = 0; q < 4; ++q) {
            red[wave][kg * 4 + q][0] = vsum[q];
            red[wave][kg * 4 + q][1] = vsq[q];
        }
    }
    __syncthreads();
    float mu[4], rs[4];
    #pragma unroll
    for (int q = 0; q < 4; ++q) {
        int rl = kg * 4 + q;
        float s = 0.f, ss = 0.f;
        #pragma unroll
        for (int w = 0; w < 4; ++w) { s += red[w][rl][0]; ss += red[w][rl][1]; }
        float m   = s * (1.f / (float)D_MODEL);
        float var = ss * (1.f / (float)D_MODEL) - m * m;
        mu[q] = m;
        rs[q] = rsqrtf(var + LN_EPSF);
    }
    #pragma unroll
    for (int j = 0; j < 8; ++j) {
        int col = colw + j * 16 + fr;
        float ga = gamma[col], be = beta[col];
        #pragma unroll
        for (int q = 0; q < 4; ++q)
            out[(size_t)(r0 + kg * 4 + q) * D_MODEL + col] =
                (acc[j][q] - mu[q]) * rs[q] * ga + be;
    }
}

// ---------------------------------------------------------------------------
extern "C" void kernel_launch(void* const* d_in, const int* in_sizes, int n_in,
                              void* d_out, int out_size, void* d_ws, size_t ws_size,
                              hipStream_t stream) {
    const float* x     = (const float*)d_in[0];
    const float* A_log = (const float*)d_in[1];
    const float* W_B   = (const float*)d_in[2];
    const float* W_C   = (const float*)d_in[3];
    const float* Dv    = (const float*)d_in[4];
    const float* Wg    = (const float*)d_in[5];
    const float* bg    = (const float*)d_in[6];
    const float* gamma = (const float*)d_in[7];
    const float* beta  = (const float*)d_in[8];
    float* out = (float*)d_out;

    const int rows = NBATCH * NSEQ;                            // 8192

    ushort* wgb    = (ushort*)d_ws;                            // 512 KB
    float*  hL     = (float*)(wgb + (size_t)D_MODEL * D_MODEL);// 512 KB
    float*  states = hL + (size_t)rows * D_STATE;              // 32 KB

    hipLaunchKernelGGL(kP, dim3(rows / 16), dim3(256), 0, stream,
                       x, A_log, W_B, Wg, wgb, hL, states);
    hipLaunchKernelGGL(kc_fused, dim3(rows / CBM), dim3(256), 0, stream,
                       x, wgb, hL, states, A_log, W_C, Dv, bg, gamma, beta, out);
}